// Round 1
// baseline (139.885 us; speedup 1.0000x reference)
//
#include <hip/hip_runtime.h>
#include <math.h>

#define SDIM 376
#define ADIM 17
#define DIN  393
#define H1   400
#define H2   300
#define TSTEPS 32
#define KPADDED 416   // 13 * 32

typedef __bf16 bf16x8 __attribute__((ext_vector_type(8)));
typedef float  f32x4  __attribute__((ext_vector_type(4)));

// ---------- K1: W1 [393][400] f32 -> W1T [400][416] bf16 (transposed, k-padded) ----------
__global__ void prep_w1t(const float* __restrict__ W1, __bf16* __restrict__ W1T) {
    int idx = blockIdx.x * 256 + threadIdx.x;
    if (idx >= H1 * KPADDED) return;
    int n = idx / KPADDED;
    int k = idx - n * KPADDED;
    float v = (k < DIN) ? W1[k * H1 + n] : 0.0f;
    W1T[idx] = (__bf16)v;
}

// ---------- K2: x1 = concat(state,action) @ W1 + b1, bf16 MFMA, BM=128 BN=80 BK=32 ----------
__global__ __launch_bounds__(256) void gemm_x1(
    const float* __restrict__ state, const float* __restrict__ action,
    const float* __restrict__ b1, const __bf16* __restrict__ W1T,
    float* __restrict__ x1) {
    // LDS: row stride 40 elems (80 B) -> 16B-aligned b128 frag reads, ~2-way banks (free)
    __shared__ alignas(16) __bf16 Al[128][40];
    __shared__ alignas(16) __bf16 Bl[80][40];

    const int tid  = threadIdx.x;
    const int wave = tid >> 6, lane = tid & 63;
    const int quad = lane >> 4, l16 = lane & 15;
    const int bm0 = blockIdx.x * 128;
    const int bn0 = blockIdx.y * 80;

    f32x4 acc[2][5];
    #pragma unroll
    for (int r = 0; r < 2; ++r)
        #pragma unroll
        for (int n = 0; n < 5; ++n)
            acc[r][n] = (f32x4){0.f, 0.f, 0.f, 0.f};

    for (int k0 = 0; k0 < KPADDED; k0 += 32) {
        __syncthreads();
        // ---- stage A tile 128x32 (convert f32 -> bf16 on the fly, concat state|action|pad)
        #pragma unroll
        for (int it = 0; it < 4; ++it) {
            int rowl = (tid >> 3) + it * 32;       // 0..127
            int kk   = (tid & 7) * 4;              // 0..28
            int grow = bm0 + rowl;
            int gk   = k0 + kk;
            float v[4];
            if (gk + 3 < SDIM) {
                const float4 f = *(const float4*)&state[grow * SDIM + gk];
                v[0] = f.x; v[1] = f.y; v[2] = f.z; v[3] = f.w;
            } else {
                #pragma unroll
                for (int e = 0; e < 4; ++e) {
                    int kg = gk + e;
                    v[e] = (kg < SDIM) ? state[grow * SDIM + kg]
                         : (kg < DIN)  ? action[grow * ADIM + kg - SDIM]
                                       : 0.0f;
                }
            }
            #pragma unroll
            for (int e = 0; e < 4; ++e) Al[rowl][kk + e] = (__bf16)v[e];
        }
        // ---- stage B tile 80x32 from prebuilt bf16 W1T
        for (int idx = tid; idx < 80 * 32; idx += 256) {
            int col = idx >> 5, kk = idx & 31;
            Bl[col][kk] = W1T[(bn0 + col) * KPADDED + k0 + kk];
        }
        __syncthreads();
        // ---- fragments + MFMA (A[m=lane&15][k=quad*8+j], B[k=quad*8+j][n=lane&15])
        bf16x8 af[2], bfr[5];
        #pragma unroll
        for (int r = 0; r < 2; ++r)
            af[r] = *(const bf16x8*)&Al[wave * 32 + r * 16 + l16][quad * 8];
        #pragma unroll
        for (int n = 0; n < 5; ++n)
            bfr[n] = *(const bf16x8*)&Bl[n * 16 + l16][quad * 8];
        #pragma unroll
        for (int r = 0; r < 2; ++r)
            #pragma unroll
            for (int n = 0; n < 5; ++n)
                acc[r][n] = __builtin_amdgcn_mfma_f32_16x16x32_bf16(af[r], bfr[n], acc[r][n], 0, 0, 0);
    }
    // ---- epilogue: C/D layout row=quad*4+reg, col=lane&15; add b1
    #pragma unroll
    for (int n = 0; n < 5; ++n) {
        int col = bn0 + n * 16 + l16;
        float bb = b1[col];
        #pragma unroll
        for (int r = 0; r < 2; ++r) {
            int mbase = bm0 + wave * 32 + r * 16 + quad * 4;
            #pragma unroll
            for (int reg = 0; reg < 4; ++reg)
                x1[(mbase + reg) * H1 + col] = acc[r][n][reg] + bb;
        }
    }
}

// ---------- K3: fused SNN time loop. One wave per batch row; no LDS, no barriers. ----------
__global__ __launch_bounds__(256) void snn_actor(
    const float* __restrict__ x1g,    // [B][400]
    const float* __restrict__ action, // [B][17]
    const float* __restrict__ W2,     // [400][300]
    const float* __restrict__ b2,     // [300]
    const float* __restrict__ W3,     // [300][17]
    const float* __restrict__ b3,     // [17]
    float* __restrict__ out) {        // [B][17]
    const int lane = threadIdx.x & 63;
    const int row  = blockIdx.x * 4 + (threadIdx.x >> 6);

    // x1 row: 7 slots/lane (448 >= 400), pad 0 (never spikes)
    float x1v[7];
    #pragma unroll
    for (int s = 0; s < 7; ++s) {
        int i = lane + 64 * s;
        x1v[s] = (i < H1) ? x1g[row * H1 + i] : 0.0f;
    }
    // b2: 5 slots/lane (320 >= 300), pad 0
    float b2v[5];
    #pragma unroll
    for (int c = 0; c < 5; ++c) {
        int j = lane + 64 * c;
        b2v[c] = (j < H2) ? b2[j] : 0.0f;
    }
    const float b3v = (lane < ADIM) ? b3[lane] : 0.0f;
    const float act = (lane < ADIM) ? action[row * ADIM + lane] : 0.0f;

    // ---- prune check: A = {i : x1 >= ~1} is a superset of all neurons that can ever
    // spike (v1_t = x1*(1-2^-t) < x1). If b2 + sum_{i in A} max(W2[i][:],0) < 1 for all
    // cols, then by induction v2 < 1 forever -> s2 == 0 -> output depends only on b3.
    float bound[5];
    #pragma unroll
    for (int c = 0; c < 5; ++c) bound[c] = b2v[c];
    #pragma unroll
    for (int s = 0; s < 7; ++s) {
        unsigned long long m = __ballot(x1v[s] >= 0.99995f);
        while (m) {
            int j = __builtin_ctzll(m);
            m &= m - 1;
            const float* wr = W2 + (s * 64 + j) * H2;
            #pragma unroll
            for (int c = 0; c < 5; ++c) {
                int col = lane + 64 * c;
                float w = (col < H2) ? wr[col] : 0.0f;
                bound[c] += fmaxf(w, 0.0f);
            }
        }
    }
    bool ok = true;
    #pragma unroll
    for (int c = 0; c < 5; ++c) ok = ok && (bound[c] < 0.999f);
    const bool safe = __all(ok);

    float vmax;
    if (safe) {
        // s2 == 0 path: x3 = b3 every step (exactly, since 0@W3 + b3 == b3)
        float v3 = 0.0f;
        vmax = -3.0e38f;
        for (int t = 0; t < TSTEPS; ++t) {
            v3 += (b3v - v3) * 0.5f;
            vmax = fmaxf(vmax, v3);
        }
    } else {
        // full event-driven sim (general correctness fallback)
        float v1[7], v2[5], v3 = 0.0f;
        vmax = -3.0e38f;
        #pragma unroll
        for (int s = 0; s < 7; ++s) v1[s] = 0.0f;
        #pragma unroll
        for (int c = 0; c < 5; ++c) v2[c] = 0.0f;
        for (int t = 0; t < TSTEPS; ++t) {
            float x2[5];
            #pragma unroll
            for (int c = 0; c < 5; ++c) x2[c] = b2v[c];
            #pragma unroll
            for (int s = 0; s < 7; ++s) {
                float v = v1[s] + (x1v[s] - v1[s]) * 0.5f;
                bool sp = v >= 1.0f;
                v1[s] = sp ? 0.0f : v;
                unsigned long long m = __ballot(sp);
                while (m) {
                    int j = __builtin_ctzll(m);
                    m &= m - 1;
                    const float* wr = W2 + (s * 64 + j) * H2;
                    #pragma unroll
                    for (int c = 0; c < 5; ++c) {
                        int col = lane + 64 * c;
                        if (col < H2) x2[c] += wr[col];
                    }
                }
            }
            float x3 = b3v;
            #pragma unroll
            for (int c = 0; c < 5; ++c) {
                float v = v2[c] + (x2[c] - v2[c]) * 0.5f;
                int col = lane + 64 * c;
                bool sp = (col < H2) && (v >= 1.0f);
                v2[c] = sp ? 0.0f : v;
                unsigned long long m = __ballot(sp);
                while (m) {
                    int j = __builtin_ctzll(m);
                    m &= m - 1;
                    int nr = c * 64 + j;
                    if (lane < ADIM) x3 += W3[nr * ADIM + lane];
                }
            }
            v3 += (x3 - v3) * 0.5f;
            vmax = fmaxf(vmax, v3);
        }
    }
    if (lane < ADIM)
        out[row * ADIM + lane] = fminf(fmaxf(0.05f * tanhf(vmax) + act, -1.0f), 1.0f);
}

extern "C" void kernel_launch(void* const* d_in, const int* in_sizes, int n_in,
                              void* d_out, int out_size, void* d_ws, size_t ws_size,
                              hipStream_t stream) {
    const float* state  = (const float*)d_in[0];
    const float* action = (const float*)d_in[1];
    const float* W1     = (const float*)d_in[2];
    const float* b1     = (const float*)d_in[3];
    const float* W2     = (const float*)d_in[4];
    const float* b2     = (const float*)d_in[5];
    const float* W3     = (const float*)d_in[6];
    const float* b3     = (const float*)d_in[7];
    float* out = (float*)d_out;

    const int B = in_sizes[0] / SDIM;  // 8192

    // ws carve: x1 [B][400] f32, then W1T [400][416] bf16
    float*  x1ws = (float*)d_ws;
    __bf16* W1T  = (__bf16*)((char*)d_ws + (size_t)B * H1 * sizeof(float));

    prep_w1t<<<(H1 * KPADDED + 255) / 256, 256, 0, stream>>>(W1, W1T);
    gemm_x1<<<dim3(B / 128, H1 / 80), 256, 0, stream>>>(state, action, b1, W1T, x1ws);
    snn_actor<<<B / 4, 256, 0, stream>>>(x1ws, action, W2, b2, W3, b3, out);
}